// Round 8
// baseline (201.148 us; speedup 1.0000x reference)
//
#include <hip/hip_runtime.h>
#include <math.h>

#define BN_EPS 1e-5f

typedef float f32x4 __attribute__((ext_vector_type(4)));
typedef short s16x8 __attribute__((ext_vector_type(8)));
typedef short s16x4 __attribute__((ext_vector_type(4)));

__device__ __forceinline__ unsigned short f2bf(float f) {
    unsigned u = __builtin_bit_cast(unsigned, f);
    u = u + 0x7FFFu + ((u >> 16) & 1u);
    return (unsigned short)(u >> 16);
}
__device__ __forceinline__ float bf2f(unsigned short s) {
    unsigned u = ((unsigned)s) << 16;
    return __builtin_bit_cast(float, u);
}

__device__ __forceinline__ void gload16(const void* g, void* l) {
    __builtin_amdgcn_global_load_lds((const __attribute__((address_space(1))) unsigned int*)g,
                                     (__attribute__((address_space(3))) unsigned int*)l,
                                     16, 0, 0);
}

// ================ fused transposes (B,C,N) fp32 -> (B,N,C) bf16; cls MLP inlined in f1 segment ======
__global__ __launch_bounds__(256) void tr_all(const float* __restrict__ f1,
                                              const float* __restrict__ f2,
                                              const float* __restrict__ f3,
                                              const float* __restrict__ f4,
                                              unsigned short* __restrict__ F1T,
                                              unsigned short* __restrict__ F2T,
                                              unsigned short* __restrict__ F3T,
                                              unsigned short* __restrict__ F4T,
                                              const int* __restrict__ lbl,
                                              const float* __restrict__ Wc1,
                                              const float* __restrict__ gc,
                                              const float* __restrict__ bc,
                                              const float* __restrict__ Wc2) {
    __shared__ float t[32][33];
    __shared__ float clsv[32];
    __shared__ float hsh[4][64];
    __shared__ float actsh[4][64];
    int bx = blockIdx.x, b = blockIdx.y;
    const float* in; unsigned short* out; int C, N, nx, seg; bool docls = false;
    if (bx < 128)      { in = f4; out = F4T; C = 1024; N = 128;  nx = 4;   seg = bx; }
    else if (bx < 384) { in = f3; out = F3T; C = 512;  N = 512;  nx = 16;  seg = bx - 128; }
    else if (bx < 896) { in = f2; out = F2T; C = 256;  N = 2048; nx = 64;  seg = bx - 384; }
    else               { in = f1; out = F1T; C = 128;  N = 8192; nx = 256; seg = bx - 896; docls = true; }
    int n0 = (seg % nx) * 32, c0 = (seg / nx) * 32;
    int tid = threadIdx.x;
    if (docls) {
        { int b2 = tid >> 6, c = tid & 63; hsh[b2][c] = Wc1[c * 16 + lbl[b2]]; }
        __syncthreads();
        if (tid < 64) {
            int c = tid;
            float m = 0.f;
            for (int b2 = 0; b2 < 4; b2++) m += hsh[b2][c];
            m *= 0.25f;
            float v = 0.f;
            for (int b2 = 0; b2 < 4; b2++) { float d = hsh[b2][c] - m; v += d * d; }
            v *= 0.25f;
            float sc = gc[c] * rsqrtf(v + BN_EPS);
            float sh = bc[c] - m * sc;
            for (int b2 = 0; b2 < 4; b2++) {
                float x = hsh[b2][c] * sc + sh;
                actsh[b2][c] = 0.5f * x * (1.f + erff(x * 0.70710678118654752f));
            }
        }
        __syncthreads();
        if (tid < 32) {
            float s = 0.f;
            for (int c = 0; c < 64; c++) s += Wc2[(size_t)(c0 + tid) * 64 + c] * actsh[b][c];
            clsv[tid] = s;
        }
        __syncthreads();
    }
    int i = tid & 31, jj = tid >> 5;
#pragma unroll
    for (int j = jj; j < 32; j += 8) {
        float v = in[((size_t)b * C + c0 + j) * N + n0 + i];
        if (docls) v += clsv[j];
        t[j][i] = v;
    }
    __syncthreads();
    int j2 = tid & 31, i2b = tid >> 5;
#pragma unroll
    for (int i2 = i2b; i2 < 32; i2 += 8)
        out[((size_t)b * N + n0 + i2) * C + c0 + j2] = f2bf(t[j2][i2]);
}

// ================ 3-NN part: per-slice exact top-3 (consecutive-j chunks, b128 LDS, med3 insert) ====
template<int CAND, int CHUNK, int STRIDE, bool PART>
__device__ __forceinline__ void knn_body(const float* __restrict__ pd,
                                         const float* __restrict__ ps,
                                         int N1, int N2total, int grp, int slice, int b,
                                         int* __restrict__ idx, float* __restrict__ w,
                                         unsigned long long* __restrict__ pk, int nslice,
                                         float* spx, float* spy, float* spz) {
    int tid = threadIdx.x;
    int cbase = slice * CAND;
    for (int g = tid; g < CAND; g += 256) {
        int s = g / CHUNK, off = g % CHUNK;
        size_t base = ((size_t)b * N2total + cbase + g) * 3;
        spx[s * STRIDE + off] = ps[base];
        spy[s * STRIDE + off] = ps[base + 1];
        spz[s * STRIDE + off] = ps[base + 2];
    }
    __syncthreads();
    int sub = tid & 7;
    int n = grp * 32 + (tid >> 3);
    size_t pb = ((size_t)b * N1 + n) * 3;
    float px = pd[pb], py = pd[pb + 1], pz = pd[pb + 2];
    float dd0 = 3.4e38f, dd1 = 3.4e38f, dd2 = 3.4e38f;
    int ii0 = 0, ii1 = 0, ii2 = 0;
    const float* rx = spx + sub * STRIDE;
    const float* ry = spy + sub * STRIDE;
    const float* rz = spz + sub * STRIDE;
    int jbase = cbase + sub * CHUNK;
    for (int t = 0; t < CHUNK; t += 4) {
        f32x4 x4 = *(const f32x4*)(rx + t);
        f32x4 y4 = *(const f32x4*)(ry + t);
        f32x4 z4 = *(const f32x4*)(rz + t);
#pragma unroll
        for (int e = 0; e < 4; e++) {
            float dx = px - x4[e], dy = py - y4[e], dz = pz - z4[e];
            float d = dx * dx + dy * dy + dz * dz;
            int j = jbase + t + e;
            bool C0 = d < dd0, C1 = d < dd1, C2 = d < dd2;
            int ni2 = C1 ? ii1 : (C2 ? j : ii2);
            int ni1 = C0 ? ii0 : (C1 ? j : ii1);
            int ni0 = C0 ? j : ii0;
            dd2 = __builtin_amdgcn_fmed3f(d, dd1, dd2);
            dd1 = __builtin_amdgcn_fmed3f(d, dd0, dd1);
            dd0 = fminf(d, dd0);
            ii0 = ni0; ii1 = ni1; ii2 = ni2;
        }
    }
    // exact u64 butterfly merge across the 8 sub-lanes
    unsigned long long k0 = ((unsigned long long)__builtin_bit_cast(unsigned, dd0) << 32) | (unsigned)ii0;
    unsigned long long k1 = ((unsigned long long)__builtin_bit_cast(unsigned, dd1) << 32) | (unsigned)ii1;
    unsigned long long k2 = ((unsigned long long)__builtin_bit_cast(unsigned, dd2) << 32) | (unsigned)ii2;
#pragma unroll
    for (int m = 1; m < 8; m <<= 1) {
        unsigned long long e0, e1, e2;
        { int lo = __shfl_xor((int)(unsigned)(k0 & 0xFFFFFFFFull), m), hi = __shfl_xor((int)(unsigned)(k0 >> 32), m);
          e0 = ((unsigned long long)(unsigned)hi << 32) | (unsigned)lo; }
        { int lo = __shfl_xor((int)(unsigned)(k1 & 0xFFFFFFFFull), m), hi = __shfl_xor((int)(unsigned)(k1 >> 32), m);
          e1 = ((unsigned long long)(unsigned)hi << 32) | (unsigned)lo; }
        { int lo = __shfl_xor((int)(unsigned)(k2 & 0xFFFFFFFFull), m), hi = __shfl_xor((int)(unsigned)(k2 >> 32), m);
          e2 = ((unsigned long long)(unsigned)hi << 32) | (unsigned)lo; }
        unsigned long long t0, t1;
        t0 = k0 > e0 ? k0 : e0; k0 = k0 < e0 ? k0 : e0; t1 = k1 > t0 ? k1 : t0; k1 = k1 < t0 ? k1 : t0; k2 = k2 < t1 ? k2 : t1;
        t0 = k0 > e1 ? k0 : e1; k0 = k0 < e1 ? k0 : e1; t1 = k1 > t0 ? k1 : t0; k1 = k1 < t0 ? k1 : t0; k2 = k2 < t1 ? k2 : t1;
        t0 = k0 > e2 ? k0 : e2; k0 = k0 < e2 ? k0 : e2; t1 = k1 > t0 ? k1 : t0; k1 = k1 < t0 ? k1 : t0; k2 = k2 < t1 ? k2 : t1;
    }
    if (sub == 0) {
        if (PART) {
            size_t o = ((size_t)(b * N1 + n) * nslice + slice) * 3;
            pk[o] = k0; pk[o + 1] = k1; pk[o + 2] = k2;
        } else {
            float f0 = __builtin_bit_cast(float, (unsigned)(k0 >> 32));
            float f1 = __builtin_bit_cast(float, (unsigned)(k1 >> 32));
            float f2 = __builtin_bit_cast(float, (unsigned)(k2 >> 32));
            float w0 = 1.f / (f0 + 1e-8f), w1 = 1.f / (f1 + 1e-8f), w2 = 1.f / (f2 + 1e-8f);
            float s = 1.f / (w0 + w1 + w2);
            size_t o = ((size_t)b * N1 + n) * 3;
            idx[o] = (int)(unsigned)(k0 & 0xFFFFFFFFull);
            idx[o + 1] = (int)(unsigned)(k1 & 0xFFFFFFFFull);
            idx[o + 2] = (int)(unsigned)(k2 & 0xFFFFFFFFull);
            w[o] = w0 * s; w[o + 1] = w1 * s; w[o + 2] = w2 * s;
        }
    }
}

__global__ __launch_bounds__(256) void knn_part(const float* __restrict__ p1,
                                                const float* __restrict__ p2,
                                                const float* __restrict__ p3,
                                                const float* __restrict__ p4,
                                                int* __restrict__ idx1, float* __restrict__ w1,
                                                int* __restrict__ idx2, float* __restrict__ w2,
                                                unsigned long long* __restrict__ pk0) {
    __shared__ float spx[8 * 72], spy[8 * 72], spz[8 * 72];
    int bx = blockIdx.x, b = blockIdx.y;
    if (bx < 16)      knn_body<128, 16, 24, false>(p3, p4, 512, 128, bx, 0, b, idx2, w2, nullptr, 1, spx, spy, spz);
    else if (bx < 80) knn_body<512, 64, 72, false>(p2, p3, 2048, 512, bx - 16, 0, b, idx1, w1, nullptr, 1, spx, spy, spz);
    else {
        int u = bx - 80;
        knn_body<512, 64, 72, true>(p1, p2, 8192, 2048, u >> 2, u & 3, b, nullptr, nullptr, pk0, 4, spx, spy, spz);
    }
}

// ================ 3-NN merge: combine 4 slice-partials per query (exact u64 order) ================
__global__ __launch_bounds__(256) void knn_merge(const unsigned long long* __restrict__ pk,
                                                 int* __restrict__ idx, float* __restrict__ w,
                                                 int NQ) {
    int q = blockIdx.x * 256 + threadIdx.x;
    if (q >= NQ) return;
    const unsigned long long* p = pk + (size_t)q * 12;
    unsigned long long k0 = ~0ull, k1 = ~0ull, k2 = ~0ull;
#pragma unroll
    for (int i = 0; i < 12; i++) {
        unsigned long long c = p[i];
        unsigned long long t0 = k0 > c ? k0 : c; k0 = k0 < c ? k0 : c;
        unsigned long long t1 = k1 > t0 ? k1 : t0; k1 = k1 < t0 ? k1 : t0;
        k2 = k2 < t1 ? k2 : t1;
    }
    float f0 = __builtin_bit_cast(float, (unsigned)(k0 >> 32));
    float f1 = __builtin_bit_cast(float, (unsigned)(k1 >> 32));
    float f2 = __builtin_bit_cast(float, (unsigned)(k2 >> 32));
    float w0 = 1.f / (f0 + 1e-8f), w1 = 1.f / (f1 + 1e-8f), w2 = 1.f / (f2 + 1e-8f);
    float s = 1.f / (w0 + w1 + w2);
    size_t o = (size_t)q * 3;
    idx[o] = (int)(unsigned)(k0 & 0xFFFFFFFFull);
    idx[o + 1] = (int)(unsigned)(k1 & 0xFFFFFFFFull);
    idx[o + 2] = (int)(unsigned)(k2 & 0xFFFFFFFFull);
    w[o] = w0 * s; w[o + 1] = w1 * s; w[o + 2] = w2 * s;
}

// ================ build x (point-major, 16B wide): XS[b][n][c] = skipT | interp(fsT) ================
__global__ __launch_bounds__(256) void build_x(const unsigned short* __restrict__ skipT,
                                               const unsigned short* __restrict__ fsT,
                                               const int* __restrict__ idx,
                                               const float* __restrict__ w,
                                               unsigned short* __restrict__ x,
                                               int Cskip, int Ctot, int Csp, int N1, int N2) {
    int cq = Ctot >> 3;
    size_t gid = (size_t)blockIdx.x * 256 + threadIdx.x;
    if (gid >= (size_t)4 * N1 * cq) return;
    int c = (int)(gid % cq) * 8;
    int n = (int)((gid / cq) % N1);
    int b = (int)(gid / ((size_t)cq * N1));
    s16x8 o;
    if (c < Cskip) {
        o = *(const s16x8*)(skipT + ((size_t)b * N1 + n) * Cskip + c);
    } else {
        int c2 = c - Cskip;
        size_t ob = ((size_t)b * N1 + n) * 3;
        int i0 = idx[ob], i1 = idx[ob + 1], i2 = idx[ob + 2];
        float w0 = w[ob], w1 = w[ob + 1], w2 = w[ob + 2];
        s16x8 v0 = *(const s16x8*)(fsT + ((size_t)b * N2 + i0) * Csp + c2);
        s16x8 v1 = *(const s16x8*)(fsT + ((size_t)b * N2 + i1) * Csp + c2);
        s16x8 v2 = *(const s16x8*)(fsT + ((size_t)b * N2 + i2) * Csp + c2);
#pragma unroll
        for (int j = 0; j < 8; j++) {
            float v = w0 * bf2f((unsigned short)v0[j]) + w1 * bf2f((unsigned short)v1[j]) + w2 * bf2f((unsigned short)v2[j]);
            o[j] = (short)f2bf(v);
        }
    }
    *(s16x8*)(x + ((size_t)b * N1 + n) * Ctot + c) = o;
}

// ================ weight prep: fold per-k BN affine into weights; bf16 W + fp32 bias ================
__global__ __launch_bounds__(256) void wprep(const float* __restrict__ W,
                                             const float* __restrict__ sc,
                                             const float* __restrict__ sh,
                                             unsigned short* __restrict__ Wb,
                                             float* __restrict__ bias,
                                             int K, int kStart) {
    int m = blockIdx.x;
    int tid = threadIdx.x;
    float bsum = 0.f;
    for (int k = tid; k < K; k += 256) {
        float wv = W[(size_t)m * K + k];
        float o = wv;
        if (sc && k >= kStart) {
            o = wv * sc[k - kStart];
            bsum += wv * sh[k - kStart];
        }
        Wb[(size_t)m * K + k] = f2bf(o);
    }
    __shared__ float ls[256];
    ls[tid] = bsum;
    __syncthreads();
    for (int o = 128; o > 0; o >>= 1) {
        if (tid < o) ls[tid] += ls[tid + o];
        __syncthreads();
    }
    if (tid == 0) bias[m] = ls[0];
}

// ================ bf16 MFMA GEMM, 64x64 tile, dbuf + global_load_lds + counted vmcnt ================
__global__ __launch_bounds__(256) void gemm64(const unsigned short* __restrict__ XT,
                                              const unsigned short* __restrict__ Wb,
                                              const float* __restrict__ bias,
                                              unsigned short* __restrict__ OutT,
                                              float* __restrict__ ps,
                                              int BN, int K, int M) {
    __shared__ unsigned short As[2][64 * 32];
    __shared__ unsigned short Bs[2][64 * 32];
    __shared__ float sred[2][2][32][2];
    int tid = threadIdx.x;
    int lane = tid & 63, wid = tid >> 6;
    int wn = wid & 1, wm = wid >> 1;
    int bx = blockIdx.x, by = blockIdx.y;

    int srow = (wid << 4) + (lane >> 2);
    int skcol = (lane & 3) << 3;
    const unsigned short* gA = XT + (size_t)(bx * 64 + srow) * K + skcol;
    const unsigned short* gB = Wb + (size_t)(by * 64 + srow) * K + skcol;

    f32x4 acc[2][2];
#pragma unroll
    for (int i = 0; i < 2; i++)
#pragma unroll
        for (int j = 0; j < 2; j++) acc[i][j] = (f32x4)0.f;

    int nt = K >> 5;
    gload16(gA, &As[0][wid * 512]);
    gload16(gB, &Bs[0][wid * 512]);

    int r16 = lane & 15, q = lane >> 4;
    for (int t = 0; t < nt; t++) {
        int cur = t & 1;
        if (t + 1 < nt) {
            int k0 = (t + 1) << 5;
            gload16(gA + k0, &As[cur ^ 1][wid * 512]);
            gload16(gB + k0, &Bs[cur ^ 1][wid * 512]);
            asm volatile("s_waitcnt vmcnt(2)" ::: "memory");
        } else {
            asm volatile("s_waitcnt vmcnt(0)" ::: "memory");
        }
        __syncthreads();
        s16x8 afr[2], bfr[2];
        afr[0] = *(const s16x8*)&As[cur][(wn * 32 + r16) * 32 + q * 8];
        afr[1] = *(const s16x8*)&As[cur][(wn * 32 + 16 + r16) * 32 + q * 8];
        bfr[0] = *(const s16x8*)&Bs[cur][(wm * 32 + r16) * 32 + q * 8];
        bfr[1] = *(const s16x8*)&Bs[cur][(wm * 32 + 16 + r16) * 32 + q * 8];
        asm volatile("s_waitcnt lgkmcnt(0)" ::: "memory");
        __builtin_amdgcn_sched_barrier(0);
        __syncthreads();
#pragma unroll
        for (int i = 0; i < 2; i++)
#pragma unroll
            for (int j = 0; j < 2; j++)
                acc[i][j] = __builtin_amdgcn_mfma_f32_16x16x32_bf16(afr[i], bfr[j], acc[i][j], 0, 0, 0);
    }

    int mc0 = by * 64 + wm * 32 + r16;
    float bv[2] = { bias[mc0], bias[mc0 + 16] };
    unsigned short* Ob = OutT + (size_t)(bx * 64) * M + by * 64;
    float s[2] = {0.f, 0.f}, qq[2] = {0.f, 0.f};
#pragma unroll
    for (int i = 0; i < 2; i++) {
#pragma unroll
        for (int j = 0; j < 2; j++) {
            int mcol = wm * 32 + j * 16 + r16;
#pragma unroll
            for (int r = 0; r < 4; r++) {
                float v = acc[i][j][r] + bv[j];
                s[j] += v; qq[j] += v * v;
                int n = wn * 32 + i * 16 + q * 4 + r;
                Ob[(size_t)n * M + mcol] = f2bf(v);
            }
        }
    }
#pragma unroll
    for (int j = 0; j < 2; j++) {
        s[j] += __shfl_xor(s[j], 16); s[j] += __shfl_xor(s[j], 32);
        qq[j] += __shfl_xor(qq[j], 16); qq[j] += __shfl_xor(qq[j], 32);
    }
    if (lane < 16) {
#pragma unroll
        for (int j = 0; j < 2; j++) {
            sred[wn][wm][j * 16 + lane][0] = s[j];
            sred[wn][wm][j * 16 + lane][1] = qq[j];
        }
    }
    __syncthreads();
    if (tid < 64) {
        int wmm = tid >> 5, c = tid & 31;
        float ssum = sred[0][wmm][c][0] + sred[1][wmm][c][0];
        float qsum = sred[0][wmm][c][1] + sred[1][wmm][c][1];
        size_t blin = (size_t)by * gridDim.x + bx;
        ps[blin * 128 + tid * 2] = ssum;
        ps[blin * 128 + tid * 2 + 1] = qsum;
    }
}

// ================ finalize BN: one block per channel ================
__global__ __launch_bounds__(256) void bn_finalize(const float* __restrict__ ps,
                                                   const float* __restrict__ g,
                                                   const float* __restrict__ bb,
                                                   float* __restrict__ sc,
                                                   float* __restrict__ sh,
                                                   int gx, int Npts) {
    int m = blockIdx.x;
    int by = m >> 6, ch = m & 63;
    float s = 0.f, q = 0.f;
    for (int bxi = threadIdx.x; bxi < gx; bxi += 256) {
        size_t blin = (size_t)by * gx + bxi;
        s += ps[blin * 128 + ch * 2];
        q += ps[blin * 128 + ch * 2 + 1];
    }
    __shared__ float ls[256], lq[256];
    ls[threadIdx.x] = s; lq[threadIdx.x] = q;
    __syncthreads();
    for (int o = 128; o > 0; o >>= 1) {
        if (threadIdx.x < o) { ls[threadIdx.x] += ls[threadIdx.x + o]; lq[threadIdx.x] += lq[threadIdx.x + o]; }
        __syncthreads();
    }
    if (threadIdx.x == 0) {
        float inv = 1.f / (float)Npts;
        float mean = ls[0] * inv;
        float var = fmaxf(lq[0] * inv - mean * mean, 0.f);
        float scale = g[m] * rsqrtf(var + BN_EPS);
        sc[m] = scale;
        sh[m] = bb[m] - mean * scale;
    }
}

// ================ final: (B,N,M) bf16 -> (B,M,N) fp32 with BN affine ================
__global__ __launch_bounds__(256) void out_bn_tr(const unsigned short* __restrict__ in,
                                                 float* __restrict__ out,
                                                 const float* __restrict__ sc,
                                                 const float* __restrict__ sh,
                                                 int M, int N) {
    __shared__ float t[32][33];
    int b = blockIdx.z;
    int n0 = blockIdx.x * 32, m0 = blockIdx.y * 32;
    int j = threadIdx.x & 31, ii = threadIdx.x >> 5;
#pragma unroll
    for (int i = ii; i < 32; i += 8)
        t[i][j] = bf2f(in[((size_t)b * N + n0 + i) * M + m0 + j]);
    __syncthreads();
    int i2 = threadIdx.x & 31, j2b = threadIdx.x >> 5;
#pragma unroll
    for (int j2 = j2b; j2 < 32; j2 += 8)
        out[((size_t)b * M + m0 + j2) * N + n0 + i2] = t[i2][j2] * sc[m0 + j2] + sh[m0 + j2];
}

extern "C" void kernel_launch(void* const* d_in, const int* in_sizes, int n_in,
                              void* d_out, int out_size, void* d_ws, size_t ws_size,
                              hipStream_t stream) {
    const float* p1 = (const float*)d_in[1];
    const float* p2 = (const float*)d_in[2];
    const float* p3 = (const float*)d_in[3];
    const float* p4 = (const float*)d_in[4];
    const float* f1 = (const float*)d_in[5];
    const float* f2 = (const float*)d_in[6];
    const float* f3 = (const float*)d_in[7];
    const float* f4 = (const float*)d_in[8];
    const int* cls = (const int*)d_in[9];
    const float* Wc1 = (const float*)d_in[10];
    const float* gc  = (const float*)d_in[11];
    const float* bc  = (const float*)d_in[12];
    const float* Wc2 = (const float*)d_in[13];
    const float* Ws2a = (const float*)d_in[14];
    const float* gs2a = (const float*)d_in[15];
    const float* bs2a = (const float*)d_in[16];
    const float* Ws2b = (const float*)d_in[17];
    const float* gs2b = (const float*)d_in[18];
    const float* bs2b = (const float*)d_in[19];
    const float* Ws1a = (const float*)d_in[20];
    const float* gs1a = (const float*)d_in[21];
    const float* bs1a = (const float*)d_in[22];
    const float* Ws1b = (const float*)d_in[23];
    const float* gs1b = (const float*)d_in[24];
    const float* bs1b = (const float*)d_in[25];
    const float* Ws0a = (const float*)d_in[26];
    const float* gs0a = (const float*)d_in[27];
    const float* bs0a = (const float*)d_in[28];
    const float* Ws0b = (const float*)d_in[29];
    const float* gs0b = (const float*)d_in[30];
    const float* bs0b = (const float*)d_in[31];

    char* ws = (char*)d_ws;
    size_t off = 0;
    auto alloc = [&](size_t bytes) { char* p = ws + off; off += (bytes + 255) & ~(size_t)255; return p; };
    unsigned short* F4T = (unsigned short*)alloc((size_t)4 * 128 * 1024 * 2);
    unsigned short* F3T = (unsigned short*)alloc((size_t)4 * 512 * 512 * 2);
    unsigned short* F2T = (unsigned short*)alloc((size_t)4 * 2048 * 256 * 2);
    unsigned short* F1T = (unsigned short*)alloc((size_t)4 * 8192 * 128 * 2);
    unsigned short* XS  = (unsigned short*)alloc((size_t)4 * 8192 * 384 * 2);
    unsigned short* YA  = (unsigned short*)alloc((size_t)4 * 8192 * 128 * 2);
    unsigned short* FN2 = (unsigned short*)alloc((size_t)4 * 512 * 512 * 2);
    unsigned short* FN1 = (unsigned short*)alloc((size_t)4 * 2048 * 256 * 2);
    unsigned short* XO  = (unsigned short*)alloc((size_t)4 * 8192 * 128 * 2);
    unsigned short* WB2a = (unsigned short*)alloc((size_t)512 * 1536 * 2);
    unsigned short* WB2b = (unsigned short*)alloc((size_t)512 * 512 * 2);
    unsigned short* WB1a = (unsigned short*)alloc((size_t)256 * 768 * 2);
    unsigned short* WB1b = (unsigned short*)alloc((size_t)256 * 256 * 2);
    unsigned short* WB0a = (unsigned short*)alloc((size_t)128 * 384 * 2);
    unsigned short* WB0b = (unsigned short*)alloc((size_t)128 * 128 * 2);
    float* BI2a = (float*)alloc(512 * 4); float* BI2b = (float*)alloc(512 * 4);
    float* BI1a = (float*)alloc(256 * 4); float* BI1b = (float*)alloc(256 * 4);
    float* BI0a = (float*)alloc(128 * 4); float* BI0b = (float*)alloc(128 * 4);
    int*   IDX0 = (int*)alloc((size_t)4 * 8192 * 3 * 4);
    float* WGT0 = (float*)alloc((size_t)4 * 8192 * 3 * 4);
    int*   IDX1 = (int*)alloc((size_t)4 * 2048 * 3 * 4);
    float* WGT1 = (float*)alloc((size_t)4 * 2048 * 3 * 4);
    int*   IDX2 = (int*)alloc((size_t)4 * 512 * 3 * 4);
    float* WGT2 = (float*)alloc((size_t)4 * 512 * 3 * 4);
    unsigned long long* PK0 = (unsigned long long*)alloc((size_t)4 * 8192 * 4 * 3 * 8);
    float* PS = (float*)alloc((size_t)1024 * 128 * 4);
    float* SC2a = (float*)alloc(512 * 4); float* SH2a = (float*)alloc(512 * 4);
    float* SC2b = (float*)alloc(512 * 4); float* SH2b = (float*)alloc(512 * 4);
    float* SC1a = (float*)alloc(512 * 4); float* SH1a = (float*)alloc(512 * 4);
    float* SC1b = (float*)alloc(512 * 4); float* SH1b = (float*)alloc(512 * 4);
    float* SC0a = (float*)alloc(512 * 4); float* SH0a = (float*)alloc(512 * 4);
    float* SC0b = (float*)alloc(512 * 4); float* SH0b = (float*)alloc(512 * 4);
    float* OUT = (float*)d_out;

    // fused transposes (+inline cls); split KNN (slices) + merge
    tr_all<<<dim3(1920, 4), 256, 0, stream>>>(f1, f2, f3, f4, F1T, F2T, F3T, F4T, cls, Wc1, gc, bc, Wc2);
    knn_part<<<dim3(1104, 4), 256, 0, stream>>>(p1, p2, p3, p4, IDX1, WGT1, IDX2, WGT2, PK0);
    knn_merge<<<(4 * 8192) / 256, 256, 0, stream>>>(PK0, IDX0, WGT0, 4 * 8192);

    // ---- stage s2: BN=2048 rows, K=1536 -> M=512, then K=512 -> 512
    wprep<<<512, 256, 0, stream>>>(Ws2a, nullptr, nullptr, WB2a, BI2a, 1536, 0);
    build_x<<<(int)(((size_t)4 * 512 * (1536 / 8) + 255) / 256), 256, 0, stream>>>(
        F3T, F4T, IDX2, WGT2, XS, 512, 1536, 1024, 512, 128);
    gemm64<<<dim3(32, 8), 256, 0, stream>>>(XS, WB2a, BI2a, YA, PS, 2048, 1536, 512);
    bn_finalize<<<512, 256, 0, stream>>>(PS, gs2a, bs2a, SC2a, SH2a, 32, 2048);
    wprep<<<512, 256, 0, stream>>>(Ws2b, SC2a, SH2a, WB2b, BI2b, 512, 0);
    gemm64<<<dim3(32, 8), 256, 0, stream>>>(YA, WB2b, BI2b, FN2, PS, 2048, 512, 512);
    bn_finalize<<<512, 256, 0, stream>>>(PS, gs2b, bs2b, SC2b, SH2b, 32, 2048);

    // ---- stage s1: BN=8192 rows, K=768 -> 256, K=256 -> 256
    wprep<<<256, 256, 0, stream>>>(Ws1a, SC2b, SH2b, WB1a, BI1a, 768, 256);
    build_x<<<(int)(((size_t)4 * 2048 * (768 / 8) + 255) / 256), 256, 0, stream>>>(
        F2T, FN2, IDX1, WGT1, XS, 256, 768, 512, 2048, 512);
    gemm64<<<dim3(128, 4), 256, 0, stream>>>(XS, WB1a, BI1a, YA, PS, 8192, 768, 256);
    bn_finalize<<<256, 256, 0, stream>>>(PS, gs1a, bs1a, SC1a, SH1a, 128, 8192);
    wprep<<<256, 256, 0, stream>>>(Ws1b, SC1a, SH1a, WB1b, BI1b, 256, 0);
    gemm64<<<dim3(128, 4), 256, 0, stream>>>(YA, WB1b, BI1b, FN1, PS, 8192, 256, 256);
    bn_finalize<<<256, 256, 0, stream>>>(PS, gs1b, bs1b, SC1b, SH1b, 128, 8192);

    // ---- stage s0: BN=32768 rows, K=384 -> 128, K=128 -> 128
    wprep<<<128, 256, 0, stream>>>(Ws0a, SC1b, SH1b, WB0a, BI0a, 384, 128);
    build_x<<<(int)(((size_t)4 * 8192 * (384 / 8) + 255) / 256), 256, 0, stream>>>(
        F1T, FN1, IDX0, WGT0, XS, 128, 384, 256, 8192, 2048);
    gemm64<<<dim3(512, 2), 256, 0, stream>>>(XS, WB0a, BI0a, YA, PS, 32768, 384, 128);
    bn_finalize<<<128, 256, 0, stream>>>(PS, gs0a, bs0a, SC0a, SH0a, 512, 32768);
    wprep<<<128, 256, 0, stream>>>(Ws0b, SC0a, SH0a, WB0b, BI0b, 128, 0);
    gemm64<<<dim3(512, 2), 256, 0, stream>>>(YA, WB0b, BI0b, XO, PS, 32768, 128, 128);
    bn_finalize<<<128, 256, 0, stream>>>(PS, gs0b, bs0b, SC0b, SH0b, 512, 32768);

    out_bn_tr<<<dim3(8192 / 32, 128 / 32, 4), 256, 0, stream>>>(XO, OUT, SC0b, SH0b, 128, 8192);
}